// Round 12
// baseline (167.279 us; speedup 1.0000x reference)
//
#include <hip/hip_runtime.h>
#include <math.h>

#define T 32
#define K 2048
#define NBLOCKS 256
#define NTHREADS 1024
#define NWAVES 16
#define HB 128                          // blocks per direction
#define CPB 16                          // columns per block (1 per wave)
#define L2E_F 1.4426950408889634f       // log2(e)
#define LN2_F 0.6931471805599453f
#define LOG2PI_F 1.8378770664093453f
#define LOG_K_F  7.6246189861593985f    // ln(2048)
#define SP_F     0.17677669529663687f   // sqrt(1/32)
#define LOG_SP_F (-1.7328679513998633f) // ln(sqrt(1/32))
#define CNORM_F  (-(LOG_SP_F) - 0.5f * LOG2PI_F)   // -ln(sp) - 0.5 ln2pi

#if __has_builtin(__builtin_amdgcn_exp2f)
#define EXP2F(x) __builtin_amdgcn_exp2f(x)
#else
#define EXP2F(x) exp2f(x)
#endif
#if __has_builtin(__builtin_amdgcn_logf)
#define LOG2F(x) __builtin_amdgcn_logf(x)
#else
#define LOG2F(x) log2f(x)
#endif

// 8-byte {value, tag} message as ONE relaxed agent-scope atomic: the data IS
// the flag (single-copy atomic), so producers need no barrier/fence/sentinel
// before consumers may read. NO agent-scope release/acquire anywhere
// (R2/R7: ~15us/step of L2 cache maintenance).
union Pack { float2 f; unsigned long long u; };
__device__ __forceinline__ float2 aload8(const float2* p) {
    Pack pk;
    pk.u = __hip_atomic_load((const unsigned long long*)p,
                             __ATOMIC_RELAXED, __HIP_MEMORY_SCOPE_AGENT);
    return pk.f;
}
__device__ __forceinline__ void astore8(float2* p, float v, int tag) {
    Pack pk; pk.f.x = v; pk.f.y = __int_as_float(tag);
    __hip_atomic_store((unsigned long long*)p, pk.u,
                       __ATOMIC_RELAXED, __HIP_MEMORY_SCOPE_AGENT);
}

// Bidirectional (16 fwd / 15 bwd steps, R11) + per-wave dataflow with ZERO
// block barriers in the chain loop. 256 blocks x 1024 threads (16 waves);
// block b owns columns [16*lb, 16*lb+16), ONE per wave. Per step, wave w:
//   1. polls ONLY its own 2 tagged messages/lane (exec-masked re-poll),
//   2. stages its 128-element (z, D) chunk to LDS, raises LDS chunkflag
//      (workgroup release = lgkmcnt drain only),
//   3. max-pass over chunks in round-robin arrival order (acquire-spin per
//      chunk), caching the row in 64 VGPRs; sets LDS done-flag,
//   4. exp2-pass from registers, publishes its column as one 8B message.
// Message r_q lives at parity q&1 with tag q+1 (tags 1..17 never match the
// 0xAA poison, so no init kernel). Ping-pong safety (per-wave induction):
// publishing r_{q+2} into parity q&1 requires having consumed ALL of
// r_{q+1}, which required every block's 16 waves to publish r_{q+1}, which
// required each to stage (= consume) its r_q chunk — so no wave can still
// be polling/reading r_q when it is overwritten. LDS parity reuse is
// guarded by the per-wave done-flags.
__global__ __launch_bounds__(NTHREADS) void fused_kernel(
    const float* __restrict__ means, const float* __restrict__ log_stds,
    const float* __restrict__ eps, float2* __restrict__ fbuf,
    float2* __restrict__ bbuf, float* __restrict__ out)
{
    __shared__ float2 shzD[2][K];    // 32 KB: (z_j, D_j) staging, parity dbuf
    __shared__ float2 lzc[T][CPB];   // own cols: (32*L2E*z, cm2 const)
    __shared__ float smu[T], sstd[T], slq2[T];
    __shared__ float red[NTHREADS];
    __shared__ int chunkflag[2][NWAVES];
    __shared__ int donef[2][NWAVES];

    const int tid  = threadIdx.x;
    const int b    = blockIdx.x;
    const bool fwd = (b < HB);
    const int lb   = fwd ? b : b - HB;
    const int col0 = lb * CPB;

    if (tid < 2 * NWAVES)      ((int*)chunkflag)[tid] = 0;
    else if (tid < 4 * NWAVES) ((int*)donef)[tid - 2 * NWAVES] = 0;

    // ---- setup: threads 0..511, thread (t = tid>>4, dcol = tid&15) ----
    if (tid < T * CPB) {
        int t = tid >> 4, dcol = tid & 15;
        float mu = means[t];
        float st = expf(log_stds[t]);
        if (dcol == 0) {
            smu[t] = mu; sstd[t] = st;
            slq2[t] = L2E_F * (logf(st) + 0.5f * LOG2PI_F);
        }
        float e = eps[t * K + col0 + dcol];
        float z = fmaf(st, e, mu);
        // (z-mu)/st == e exactly: log_q = -0.5 e^2 - ln(st) - 0.5 ln2pi
        float log_q = fmaf(-0.5f * e, e, -logf(st) - 0.5f * LOG2PI_F);
        float tz2 = (32.0f * L2E_F) * z;
        if (fwd) {
            float cm2 = fmaf((-16.0f * L2E_F) * z, z,
                             L2E_F * (CNORM_F - log_q)) - 11.0f;   // log2K = 11
            lzc[t][dcol] = make_float2(tz2, cm2);
            if (t == 0) {   // seed r_0: tag 1, parity 0
                float r0 = fmaf(-16.0f * z, z, CNORM_F) - log_q;
                astore8(&fbuf[col0 + dcol], r0 * L2E_F, 1);
            }
        } else {
            float cm2 = fmaf((-16.0f * L2E_F) * z, z, L2E_F * CNORM_F) - 11.0f;
            lzc[t][dcol] = make_float2(tz2, cm2);
            if (t == T - 1) {   // seed c_31 = likelihood: tag 1, parity 0
                float d = 0.5f - z;
                float c31 = fmaf(-0.5f * d, d, -0.5f * LOG2PI_F);
                astore8(&bbuf[col0 + dcol], c31 * L2E_F, 1);
            }
        }
    }
    __syncthreads();    // LDS init visible; the ONLY block barrier pre-join

    const int lane = tid & 63;
    const int wave = tid >> 6;          // 0..15: column col0 + wave, chunk wave
    float2* mybuf = fwd ? fbuf : bbuf;
    const int nstep = fwd ? 16 : 15;
    const int j0 = wave * 128 + lane;
    const int j1 = j0 + 64;

    for (int p = 0; p < nstep; ++p) {
        const int par  = p & 1;
        const int tg   = p + 1;
        const int tin  = fwd ? p : 31 - p;
        const int town = fwd ? p + 1 : 30 - p;
        const float mu_i  = smu[tin];
        const float std_i = sstd[tin];
        const float lqc   = slq2[tin];

        // ---- pre-poll: z and D-addend for own 2 elements (r-independent) ----
        float e0 = eps[tin * K + j0];
        float e1 = eps[tin * K + j1];
        float z0 = fmaf(std_i, e0, mu_i);
        float z1 = fmaf(std_i, e1, mu_i);
        float b0 = fwd ? 0.0f : fmaf((0.5f * L2E_F) * e0, e0, lqc);
        float b1 = fwd ? 0.0f : fmaf((0.5f * L2E_F) * e1, e1, lqc);
        float d0 = fmaf((-16.0f * L2E_F) * z0, z0, b0);
        float d1 = fmaf((-16.0f * L2E_F) * z1, z1, b1);

        // ---- wait until ALL waves finished reading this LDS parity (p-2) ----
        {
            const int need = p - 1;
            for (;;) {
                int v = (lane < NWAVES)
                    ? __hip_atomic_load(&donef[par][lane], __ATOMIC_ACQUIRE,
                                        __HIP_MEMORY_SCOPE_WORKGROUP)
                    : 0x7fffffff;
                if (__all(v >= need)) break;
            }
        }

        // ---- poll ONLY own 2 tagged messages (exec-masked re-poll) ----
        float2* mrow = mybuf + par * K;
        float2 v0 = aload8(&mrow[j0]);
        float2 v1 = aload8(&mrow[j1]);
        while (!__all((__float_as_int(v0.y) == tg) &
                      (__float_as_int(v1.y) == tg))) {
            __builtin_amdgcn_s_sleep(1);
            if (__float_as_int(v0.y) != tg) v0 = aload8(&mrow[j0]);
            if (__float_as_int(v1.y) != tg) v1 = aload8(&mrow[j1]);
        }

        // ---- stage own chunk, raise chunk flag (lgkmcnt-only release) ----
        shzD[par][j0] = make_float2(z0, v0.x + d0);
        shzD[par][j1] = make_float2(z1, v1.x + d1);
        __hip_atomic_store(&chunkflag[par][wave], tg, __ATOMIC_RELEASE,
                           __HIP_MEMORY_SCOPE_WORKGROUP);

        // ---- max pass over chunks in round-robin order, row into VGPRs ----
        float2 zc = lzc[town][wave];
        float tz2 = zc.x, cm2 = zc.y;
        float2 fr[32];
        float mM = -INFINITY;
        #pragma unroll
        for (int i = 0; i < 16; ++i) {
            int cw = (wave + i) & 15;
            if (i > 0) {
                while (__hip_atomic_load(&chunkflag[par][cw], __ATOMIC_ACQUIRE,
                                         __HIP_MEMORY_SCOPE_WORKGROUP) < tg) {}
            }
            float2 a = shzD[par][cw * 128 + lane];
            float2 c = shzD[par][cw * 128 + 64 + lane];
            fr[2 * i]     = a;
            fr[2 * i + 1] = c;
            // u_j = rho_j - 16*L2E*(z'-z_j)^2 + const = fma(tz2, z_j, D_j)
            mM = fmaxf(mM, fmaxf(fmaf(tz2, a.x, a.y), fmaf(tz2, c.x, c.y)));
        }
        // LDS reads done for this parity (pass 2 is register-only)
        __hip_atomic_store(&donef[par][wave], tg, __ATOMIC_RELEASE,
                           __HIP_MEMORY_SCOPE_WORKGROUP);

        #pragma unroll
        for (int off = 32; off >= 1; off >>= 1)
            mM = fmaxf(mM, __shfl_xor(mM, off, 64));
        float ss = 0.0f;
        #pragma unroll
        for (int i = 0; i < 32; ++i)
            ss += EXP2F(fmaf(tz2, fr[i].x, fr[i].y) - mM);
        #pragma unroll
        for (int off = 32; off >= 1; off >>= 1)
            ss += __shfl_xor(ss, off, 64);

        // ---- publish own column immediately: one 8B message, no barrier ----
        if (lane == 0)
            astore8(&mybuf[(par ^ 1) * K + col0 + wave],
                    cm2 + mM + LOG2F(ss), p + 2);
    }

    // ---- join: out = lse_j(r_16[j] + c_16[j]) - lnK, block 0 only ----
    if (b == 0) {
        __syncthreads();
        // r_16: fbuf parity 0, tag 17.  c_16: bbuf parity 1, tag 16.
        const int jA = tid, jB = tid + NTHREADS;
        float2 a0 = aload8(&fbuf[jA]);
        float2 a1 = aload8(&fbuf[jB]);
        float2 c0 = aload8(&bbuf[K + jA]);
        float2 c1 = aload8(&bbuf[K + jB]);
        for (;;) {
            bool ok = (__float_as_int(a0.y) == 17) & (__float_as_int(a1.y) == 17)
                    & (__float_as_int(c0.y) == 16) & (__float_as_int(c1.y) == 16);
            if (__all(ok)) break;
            __builtin_amdgcn_s_sleep(1);
            if (__float_as_int(a0.y) != 17) a0 = aload8(&fbuf[jA]);
            if (__float_as_int(a1.y) != 17) a1 = aload8(&fbuf[jB]);
            if (__float_as_int(c0.y) != 16) c0 = aload8(&bbuf[K + jA]);
            if (__float_as_int(c1.y) != 16) c1 = aload8(&bbuf[K + jB]);
        }
        float vA = a0.x + c0.x;
        float vB = a1.x + c1.x;
        float m = fmaxf(vA, vB);
        red[tid] = m; __syncthreads();
        for (int off = NTHREADS / 2; off >= 1; off >>= 1) {
            if (tid < off) red[tid] = fmaxf(red[tid], red[tid + off]);
            __syncthreads();
        }
        m = red[0]; __syncthreads();
        float ssum = EXP2F(vA - m) + EXP2F(vB - m);
        red[tid] = ssum; __syncthreads();
        for (int off = NTHREADS / 2; off >= 1; off >>= 1) {
            if (tid < off) red[tid] += red[tid + off];
            __syncthreads();
        }
        if (tid == 0) out[0] = LN2_F * (m + LOG2F(red[0]) - 11.0f);
    }
}

extern "C" void kernel_launch(void* const* d_in, const int* in_sizes, int n_in,
                              void* d_out, int out_size, void* d_ws, size_t ws_size,
                              hipStream_t stream) {
    const float* means    = (const float*)d_in[0];
    const float* log_stds = (const float*)d_in[1];
    const float* eps      = (const float*)d_in[2];
    float* out = (float*)d_out;

    float2* fbuf = (float2*)d_ws;       // 2*K fwd {val,tag} ping-pong (32 KB)
    float2* bbuf = fbuf + 2 * K;        // 2*K bwd {val,tag} ping-pong (32 KB)

    fused_kernel<<<NBLOCKS, NTHREADS, 0, stream>>>(
        means, log_stds, eps, fbuf, bbuf, out);
}